// Round 16
// baseline (91.557 us; speedup 1.0000x reference)
//
#include <hip/hip_runtime.h>

#define LSEQ 8192
#define NBAT 16
#define DMOD 16
#define DINN 32
#define DSTA 16
#define CL   32
#define NCH  (LSEQ / CL)            // 256 chunks per batch
#define NCHT (NBAT * NCH)           // 4096
#define NROWS (NBAT * LSEQ)         // 131072
#define SUMN ((size_t)NCHT * 512)
#define NSEG 8
#define SEGC (NCH / NSEG)           // 32
#define RECU 800                    // u32 per chunk: y-pairs[16] C-pairs[8] p0[1] x32
#define LOG2E 1.44269504f
#define FENCE() asm volatile("" ::: "memory")

typedef __attribute__((ext_vector_type(8))) short bf16x8;
typedef __attribute__((ext_vector_type(4))) float f32x4;

__device__ __forceinline__ float fsilu(float v) { return v / (1.f + __expf(-v)); }
__device__ __forceinline__ float fsoftplus(float v) {
  return v > 20.f ? v : __logf(1.f + __expf(v));
}
__device__ __forceinline__ unsigned packbf(float a, float b) {
  unsigned r;
  asm("v_cvt_pk_bf16_f32 %0, %1, %2" : "=v"(r) : "v"(a), "v"(b));
  return r;
}
__device__ __forceinline__ short f2bf(float f) {
  return (short)(packbf(f, f) & 0xffffu);
}
__device__ __forceinline__ float bf2f(short s) {
  union { unsigned u; float f; } v;
  v.u = ((unsigned)(unsigned short)s) << 16;
  return v.f;
}
__device__ __forceinline__ float bflo(unsigned u) {
  union { unsigned a; float f; } v; v.a = u << 16; return v.f;
}
__device__ __forceinline__ float bfhi(unsigned u) {
  union { unsigned a; float f; } v; v.a = u & 0xffff0000u; return v.f;
}

__device__ __forceinline__ void load_x_row(const float* __restrict__ x, long r,
                                           float* __restrict__ xr) {
  const float4* xp = reinterpret_cast<const float4*>(x + r * DMOD);
  float4 v0 = xp[0], v1 = xp[1], v2 = xp[2], v3 = xp[3];
  xr[0] = v0.x; xr[1] = v0.y; xr[2] = v0.z; xr[3] = v0.w;
  xr[4] = v1.x; xr[5] = v1.y; xr[6] = v1.z; xr[7] = v1.w;
  xr[8] = v2.x; xr[9] = v2.y; xr[10] = v2.z; xr[11] = v2.w;
  xr[12] = v3.x; xr[13] = v3.y; xr[14] = v3.z; xr[15] = v3.w;
}

__device__ __forceinline__ f32x4 mm(bf16x8 a, bf16x8 b, f32x4 c) {
  return __builtin_amdgcn_mfma_f32_16x16x32_bf16(a, b, c, 0, 0, 0);
}
__device__ __forceinline__ bf16x8 bfrag(const float* __restrict__ W, int ldw,
                                        int coloff, int col, int kg, int kreal) {
  bf16x8 b = {0, 0, 0, 0, 0, 0, 0, 0};
#pragma unroll
  for (int e = 0; e < 8; e++) {
    int k = kg * 8 + e;
    if (k < kreal) b[e] = f2bf(W[k * ldw + coloff + col]);
  }
  return b;
}

// ---- K1: prep + local scan. 1 block (128 thr = 2 waves) = 1 chunk (32 rows).
// Grid 4096.  ~7 KB LDS -> up to 16 blocks/CU (32 waves, 100% occupancy).
__global__ __launch_bounds__(128) void k_prep(
    const float* __restrict__ x, const float* __restrict__ rms1w,
    const float* __restrict__ ipw, const float* __restrict__ cw,
    const float* __restrict__ cb, const float* __restrict__ xpw,
    const float* __restrict__ dtw, const float* __restrict__ dtb,
    const float* __restrict__ A_log, const float* __restrict__ Dskip,
    unsigned* __restrict__ rec, float* __restrict__ Pb,
    float* __restrict__ Hb) {
  __shared__ short XM[35][36];  // xm bf16 (3 halo + 32); later prj B/C/p0
  __shared__ short X0[32][32];  // x0 bf16 cols 0..15; later dt bf16 cols 0..31
  __shared__ short XC[32][40];  // xc bf16 cols 0..31; y overwrites in F
  int t = threadIdx.x;
  int l = t & 63, wid = t >> 6;
  int col = l & 15, kg = l >> 4;
  int chunk = blockIdx.x;
  long row0 = (long)chunk * CL;
  bool first = (chunk & (NCH - 1)) == 0;
  const f32x4 zero4 = {0.f, 0.f, 0.f, 0.f};

  bf16x8 Bip0 = bfrag(ipw, 64, 0, col, kg, 16);
  bf16x8 Bip1 = bfrag(ipw, 64, 16, col, kg, 16);
  bf16x8 Bdt, Bb, Bc;
#pragma unroll
  for (int e = 0; e < 8; e++) {
    int k = kg * 8 + e;
    Bdt[e] = (col == 0) ? f2bf(xpw[k * 33]) : (short)0;
    Bb[e] = f2bf(xpw[k * 33 + 1 + col]);
    Bc[e] = f2bf(xpw[k * 33 + 17 + col]);
  }

  // Phase A: rmsnorm -> x0 bf16 (4 thr/row, 4 elems each)
  {
    int row = t >> 2, q = t & 3;
    const float4* xp =
        reinterpret_cast<const float4*>(x + (row0 + row) * DMOD + q * 4);
    float4 v = xp[0];
    float ss = v.x * v.x + v.y * v.y + v.z * v.z + v.w * v.w;
    ss += __shfl_xor(ss, 1);
    ss += __shfl_xor(ss, 2);
    float inv1 = rsqrtf(ss * (1.f / 16.f) + 1e-6f);
    unsigned u0 = packbf(v.x * inv1 * rms1w[q * 4], v.y * inv1 * rms1w[q * 4 + 1]);
    unsigned u1 = packbf(v.z * inv1 * rms1w[q * 4 + 2], v.w * inv1 * rms1w[q * 4 + 3]);
    *reinterpret_cast<uint2*>(&X0[row][q * 4]) = make_uint2(u0, u1);
  }
  // halo xm: threads 0..95 -> (h = t>>5, col k = t&31)
  if (t < 96) {
    int h = t >> 5, k = t & 31;
    float a0 = 0.f;
    if (!first) {
      float xr[16];
      load_x_row(x, row0 - 3 + h, xr);
      float ss = 0.f;
#pragma unroll
      for (int i = 0; i < 16; i++) ss += xr[i] * xr[i];
      float inv1 = rsqrtf(ss * (1.f / 16.f) + 1e-6f);
#pragma unroll
      for (int i = 0; i < 16; i++)
        a0 = fmaf(xr[i] * inv1 * rms1w[i], ipw[i * 64 + k], a0);
    }
    XM[h][k] = f2bf(a0);
  }
  FENCE();

  // Phase B: xm = x0 @ ipw[:, 0:32]; wave w -> tile rows w*16..w*16+15
  {
    int arow = wid * 16 + col;
    bf16x8 a = {0, 0, 0, 0, 0, 0, 0, 0};
    if (kg < 2) a = *reinterpret_cast<const bf16x8*>(&X0[arow][kg * 8]);
    f32x4 m0 = mm(a, Bip0, zero4);
    f32x4 m1 = mm(a, Bip1, zero4);
    int orow = 3 + wid * 16 + kg * 4;
#pragma unroll
    for (int reg = 0; reg < 4; reg++) {
      unsigned p = packbf(m0[reg], m1[reg]);
      XM[orow + reg][col] = (short)(p & 0xffffu);
      XM[orow + reg][col + 16] = (short)(p >> 16);
    }
  }
  __syncthreads();  // halo/xm cross-wave before conv

  // Phase C: causal conv + silu; thread (row=t>>2, q=t&3) does 8 d's
  {
    int row = t >> 2, q = t & 3;
    unsigned u[4];
#pragma unroll
    for (int dp = 0; dp < 4; dp++) {
      int d = q * 8 + dp * 2;
      float ce = cb[d], co = cb[d + 1];
#pragma unroll
      for (int k = 0; k < 4; k++) {
        unsigned xu = *reinterpret_cast<const unsigned*>(&XM[row + k][d]);
        ce = fmaf(cw[d * 4 + k], bflo(xu), ce);
        co = fmaf(cw[(d + 1) * 4 + k], bfhi(xu), co);
      }
      u[dp] = packbf(fsilu(ce), fsilu(co));
    }
    *reinterpret_cast<uint4*>(&XC[row][q * 8]) = make_uint4(u[0], u[1], u[2], u[3]);
  }
  __syncthreads();  // conv reads of xm done before prj overwrites XM

  // Phase D: proj MFMA -> prj into XM rows 3..34 (B 0..15, C 16..31, p0 @32)
  {
    int arow = wid * 16 + col;
    bf16x8 a2 = *reinterpret_cast<const bf16x8*>(&XC[arow][kg * 8]);
    f32x4 pd = mm(a2, Bdt, zero4);
    f32x4 pb = mm(a2, Bb, zero4);
    f32x4 pc = mm(a2, Bc, zero4);
    int orow = 3 + wid * 16 + kg * 4;
#pragma unroll
    for (int reg = 0; reg < 4; reg++) {
      unsigned p = packbf(pb[reg], pc[reg]);
      XM[orow + reg][col] = (short)(p & 0xffffu);
      XM[orow + reg][16 + col] = (short)(p >> 16);
      if (col == 0) XM[orow + reg][32] = f2bf(pd[reg]);
    }
  }
  FENCE();

  // Phase D2: dt = softplus(p0*dtw+dtb) -> X0 cols 0..31 (x0 dead; same-wave rows)
  {
    int row = t >> 2, q = t & 3;
    float p0 = bf2f(XM[3 + row][32]);
    unsigned u[4];
#pragma unroll
    for (int dp = 0; dp < 4; dp++) {
      int d = q * 8 + dp * 2;
      u[dp] = packbf(fsoftplus(fmaf(p0, dtw[d], dtb[d])),
                     fsoftplus(fmaf(p0, dtw[d + 1], dtb[d + 1])));
    }
    *reinterpret_cast<uint4*>(&X0[row][q * 8]) = make_uint4(u[0], u[1], u[2], u[3]);
  }
  __syncthreads();  // dt/prj cross-wave before scan

  // Phase F: scan; thread -> (d = t>>2, 4 states s4..s4+3)
  {
    int d = t >> 2, s4 = (t & 3) << 2;
    float4 al = *reinterpret_cast<const float4*>(A_log + d * DSTA + s4);
    float Ad0 = -__expf(al.x) * LOG2E, Ad1 = -__expf(al.y) * LOG2E;
    float Ad2 = -__expf(al.z) * LOG2E, Ad3 = -__expf(al.w) * LOG2E;
    float dskd = Dskip[d];
    bool wy = (t & 3) == 0;
    float H0 = 0.f, H1 = 0.f, H2 = 0.f, H3 = 0.f, cum = 0.f;
#pragma unroll 4
    for (int li = 0; li < CL; li++) {
      float dt = bf2f(X0[li][d]);
      float xcv = bf2f(XC[li][d]);
      float dx = dt * xcv;
      cum += dt;
      uint2 bu = *reinterpret_cast<const uint2*>(&XM[3 + li][s4]);
      uint2 cu = *reinterpret_cast<const uint2*>(&XM[3 + li][16 + s4]);
      float a;
      a = __builtin_amdgcn_exp2f(dt * Ad0); H0 = fmaf(a, H0, dx * bflo(bu.x));
      a = __builtin_amdgcn_exp2f(dt * Ad1); H1 = fmaf(a, H1, dx * bfhi(bu.x));
      a = __builtin_amdgcn_exp2f(dt * Ad2); H2 = fmaf(a, H2, dx * bflo(bu.y));
      a = __builtin_amdgcn_exp2f(dt * Ad3); H3 = fmaf(a, H3, dx * bfhi(bu.y));
      float y = bflo(cu.x) * H0;
      y = fmaf(bfhi(cu.x), H1, y);
      y = fmaf(bflo(cu.y), H2, y);
      y = fmaf(bfhi(cu.y), H3, y);
      y += __shfl_xor(y, 1);
      y += __shfl_xor(y, 2);
      if (wy) XC[li][d] = f2bf(fmaf(dskd, xcv, y));
    }
    size_t sb_ = (size_t)chunk * 512 + (size_t)(d * 16 + s4);
    *reinterpret_cast<float4*>(Pb + sb_) = make_float4(
        __builtin_amdgcn_exp2f(cum * Ad0), __builtin_amdgcn_exp2f(cum * Ad1),
        __builtin_amdgcn_exp2f(cum * Ad2), __builtin_amdgcn_exp2f(cum * Ad3));
    *reinterpret_cast<float4*>(Hb + sb_) = make_float4(H0, H1, H2, H3);
  }
  __syncthreads();  // y cross-wave before record write

  // Phase G: record writes (coalesced)
  {
    unsigned* rb = rec + (size_t)chunk * RECU;
#pragma unroll
    for (int i = 0; i < 7; i++) {
      int idx = i * 128 + t;
      if (idx < 800) {
        int c = idx >> 5, r = idx & 31;
        unsigned val;
        if (c < 16)
          val = *reinterpret_cast<const unsigned*>(&XC[r][2 * c]);
        else if (c < 24)
          val = *reinterpret_cast<const unsigned*>(&XM[3 + r][16 + 2 * (c - 16)]);
        else
          val = (unsigned)(unsigned short)XM[3 + r][32];
        rb[idx] = val;
      }
    }
  }
}

// ---- K2a: segmented exclusive scan IN PLACE + segment summaries
__global__ __launch_bounds__(256) void k_seg(float* __restrict__ Pb,
                                             float* __restrict__ Hb,
                                             float* __restrict__ segP,
                                             float* __restrict__ segH) {
  int g = blockIdx.x * 256 + threadIdx.x;  // 65536
  int b = g >> 12;
  int rem = g & 4095;
  int seg = rem >> 9, st = rem & 511;
  size_t o = ((size_t)(b * NCH + seg * SEGC)) * 512 + st;
  float h = 0.f, p = 1.f;
#pragma unroll 4
  for (int c = 0; c < SEGC; c++) {
    float P = Pb[o], H = Hb[o];
    Pb[o] = p;
    Hb[o] = h;
    h = fmaf(P, h, H);
    p *= P;
    o += 512;
  }
  size_t so = (size_t)(b * NSEG + seg) * 512 + st;
  segP[so] = p;
  segH[so] = h;
}

// ---- K2b: scan over segment summaries -> segment start states
__global__ __launch_bounds__(256) void k_carry(const float* __restrict__ segP,
                                               const float* __restrict__ segH,
                                               float* __restrict__ carry) {
  int g = blockIdx.x * 256 + threadIdx.x;  // 8192
  int b = g >> 9, st = g & 511;
  float h = 0.f;
#pragma unroll
  for (int s = 0; s < NSEG; s++) {
    size_t so = (size_t)(b * NSEG + s) * 512 + st;
    carry[so] = h;
    h = fmaf(segP[so], h, segH[so]);
  }
}

// ---- K3: h0-correction + MFMA epilogue. 1 block (128 thr) = 1 chunk.
__global__ __launch_bounds__(128) void k_mlp(
    const unsigned* __restrict__ rec, const float* __restrict__ x,
    const float* __restrict__ A_log, const float* __restrict__ Pb,
    const float* __restrict__ Hb, const float* __restrict__ carry,
    const float* __restrict__ dtw, const float* __restrict__ dtb,
    const float* __restrict__ rms1w, const float* __restrict__ ipw,
    const float* __restrict__ opw, const float* __restrict__ rms2w,
    const float* __restrict__ f1w, const float* __restrict__ f1b,
    const float* __restrict__ f2w, const float* __restrict__ f2b,
    const float* __restrict__ f3w, const float* __restrict__ f3b,
    float* __restrict__ out) {
  __shared__ float Ads[512];    // pre-scaled by LOG2E
  __shared__ float h0w[512];
  __shared__ short sbx[32][24]; // x0 bf16
  __shared__ short sby[32][40]; // yfin -> yo -> x2 -> h1 -> h2 (bf16)
  int t = threadIdx.x;
  int l = t & 63, wid = t >> 6;
  int gc = blockIdx.x;
  long row0 = (long)gc * CL;

#pragma unroll
  for (int i = 0; i < 4; i++) {
    int idx = i * 128 + t;
    Ads[idx] = -__expf(A_log[idx]) * LOG2E;
  }
  // h0 for this chunk (4 states/thread)
  {
    size_t o = (size_t)gc * 512 + (size_t)(t * 4);
    int b = gc >> 8, seg = (gc >> 5) & 7;
    size_t co = (size_t)(b * NSEG + seg) * 512 + (size_t)(t * 4);
    float4 pv = *reinterpret_cast<const float4*>(Pb + o);
    float4 hv = *reinterpret_cast<const float4*>(Hb + o);
    float4 cv = *reinterpret_cast<const float4*>(carry + co);
    *reinterpret_cast<float4*>(&h0w[t * 4]) =
        make_float4(fmaf(pv.x, cv.x, hv.x), fmaf(pv.y, cv.y, hv.y),
                    fmaf(pv.z, cv.z, hv.z), fmaf(pv.w, cv.w, hv.w));
  }
  // rmsnorm -> x0 bf16 (4 thr/row)
  {
    int row = t >> 2, q = t & 3;
    const float4* xp =
        reinterpret_cast<const float4*>(x + (row0 + row) * DMOD + q * 4);
    float4 v = xp[0];
    float ss = v.x * v.x + v.y * v.y + v.z * v.z + v.w * v.w;
    ss += __shfl_xor(ss, 1);
    ss += __shfl_xor(ss, 2);
    float inv1 = rsqrtf(ss * (1.f / 16.f) + 1e-6f);
    unsigned u0 = packbf(v.x * inv1 * rms1w[q * 4], v.y * inv1 * rms1w[q * 4 + 1]);
    unsigned u1 = packbf(v.z * inv1 * rms1w[q * 4 + 2], v.w * inv1 * rms1w[q * 4 + 3]);
    *reinterpret_cast<uint2*>(&sbx[row][q * 4]) = make_uint2(u0, u1);
  }
  __syncthreads();

  // correction: yfin = ypre + sum_s exp2(Ads*cumdt)*C*h0
  // thread (half = t>>5 in 0..3, r = t&31) handles 4 C-pairs (8 d's)
  {
    int half = t >> 5, r = t & 31;
    const unsigned* rb = rec + (size_t)gc * RECU;
    float Cv[16];
#pragma unroll
    for (int c = 0; c < 8; c++) {
      unsigned u = rb[(16 + c) * 32 + r];
      Cv[2 * c] = bflo(u);
      Cv[2 * c + 1] = bfhi(u);
    }
    float p0 = bflo(rb[24 * 32 + r]);
#pragma unroll
    for (int cc = 0; cc < 4; cc++) {
      int c = half * 4 + cc;
      int d0 = 2 * c, d1 = 2 * c + 1;
      float cd0 = fsoftplus(fmaf(p0, dtw[d0], dtb[d0]));
      float cd1 = fsoftplus(fmaf(p0, dtw[d1], dtb[d1]));
#pragma unroll
      for (int dl = 1; dl < 32; dl <<= 1) {
        float u0 = __shfl_up(cd0, dl, 32);
        float u1 = __shfl_up(cd1, dl, 32);
        if (r >= dl) { cd0 += u0; cd1 += u1; }
      }
      unsigned yu = rb[c * 32 + r];
      float acc0 = bflo(yu), acc1 = bfhi(yu);
      int dof0 = d0 * 16, dof1 = d1 * 16;
#pragma unroll
      for (int s = 0; s < 16; s++) {
        float e0 = __builtin_amdgcn_exp2f(Ads[dof0 + s] * cd0);
        float e1 = __builtin_amdgcn_exp2f(Ads[dof1 + s] * cd1);
        acc0 = fmaf(e0 * Cv[s], h0w[dof0 + s], acc0);
        acc1 = fmaf(e1 * Cv[s], h0w[dof1 + s], acc1);
      }
      *reinterpret_cast<unsigned*>(&sby[r][2 * c]) = packbf(acc0, acc1);
    }
  }
  __syncthreads();

  // MFMA epilogue: wave w owns tile rows w*16..w*16+15
  {
    int col = l & 15, kg = l >> 4;
    bf16x8 Bz0 = bfrag(ipw + 32, 64, 0, col, kg, 16);
    bf16x8 Bz1 = bfrag(ipw + 32, 64, 16, col, kg, 16);
    bf16x8 Bop = bfrag(opw, 16, 0, col, kg, 32);
    bf16x8 Bf1_0 = bfrag(f1w, 32, 0, col, kg, 16);
    bf16x8 Bf1_1 = bfrag(f1w, 32, 16, col, kg, 16);
    bf16x8 Bf2_0 = bfrag(f2w, 32, 0, col, kg, 32);
    bf16x8 Bf2_1 = bfrag(f2w, 32, 16, col, kg, 32);
    bf16x8 Bf3 = bfrag(f3w, 16, 0, col, kg, 32);
    float b1_0 = f1b[col], b1_1 = f1b[16 + col];
    float b2_0 = f2b[col], b2_1 = f2b[16 + col];
    float b3c = f3b[col], rw2 = rms2w[col];
    const f32x4 zero4 = {0.f, 0.f, 0.f, 0.f};
    int tile0 = wid * 16;
    bf16x8 ax0 = {0, 0, 0, 0, 0, 0, 0, 0};
    if (kg < 2)
      ax0 = *reinterpret_cast<const bf16x8*>(&sbx[tile0 + col][kg * 8]);
    f32x4 zf0 = mm(ax0, Bz0, zero4);
    f32x4 zf1 = mm(ax0, Bz1, zero4);
#pragma unroll
    for (int reg = 0; reg < 4; reg++) {
      int lrow = tile0 + kg * 4 + reg;
      float y0 = bf2f(sby[lrow][col]);
      float y1 = bf2f(sby[lrow][16 + col]);
      unsigned p = packbf(y0 * fsilu(zf0[reg]), y1 * fsilu(zf1[reg]));
      sby[lrow][col] = (short)(p & 0xffffu);
      sby[lrow][16 + col] = (short)(p >> 16);
    }
    FENCE();
    bf16x8 ayo = *reinterpret_cast<const bf16x8*>(&sby[tile0 + col][kg * 8]);
    f32x4 x1f = mm(ayo, Bop, zero4);
    float xres[4];
#pragma unroll
    for (int reg = 0; reg < 4; reg++) {
      long grow = row0 + tile0 + kg * 4 + reg;
      xres[reg] = x1f[reg] + x[grow * 16 + col];
    }
#pragma unroll
    for (int reg = 0; reg < 4; reg++) {
      float ss = xres[reg] * xres[reg];
      ss += __shfl_xor(ss, 1);
      ss += __shfl_xor(ss, 2);
      ss += __shfl_xor(ss, 4);
      ss += __shfl_xor(ss, 8);
      float inv2 = rsqrtf(ss * (1.f / 16.f) + 1e-6f);
      sby[tile0 + kg * 4 + reg][col] = f2bf(xres[reg] * inv2 * rw2);
    }
    FENCE();
    bf16x8 ax2 = {0, 0, 0, 0, 0, 0, 0, 0};
    if (kg < 2)
      ax2 = *reinterpret_cast<const bf16x8*>(&sby[tile0 + col][kg * 8]);
    f32x4 h1f0 = mm(ax2, Bf1_0, zero4);
    f32x4 h1f1 = mm(ax2, Bf1_1, zero4);
#pragma unroll
    for (int reg = 0; reg < 4; reg++) {
      int lrow = tile0 + kg * 4 + reg;
      unsigned p = packbf(fmaxf(h1f0[reg] + b1_0, 0.f),
                          fmaxf(h1f1[reg] + b1_1, 0.f));
      sby[lrow][col] = (short)(p & 0xffffu);
      sby[lrow][16 + col] = (short)(p >> 16);
    }
    FENCE();
    bf16x8 ah1 = *reinterpret_cast<const bf16x8*>(&sby[tile0 + col][kg * 8]);
    f32x4 h2f0 = mm(ah1, Bf2_0, zero4);
    f32x4 h2f1 = mm(ah1, Bf2_1, zero4);
#pragma unroll
    for (int reg = 0; reg < 4; reg++) {
      int lrow = tile0 + kg * 4 + reg;
      unsigned p = packbf(fmaxf(h2f0[reg] + b2_0, 0.f),
                          fmaxf(h2f1[reg] + b2_1, 0.f));
      sby[lrow][col] = (short)(p & 0xffffu);
      sby[lrow][16 + col] = (short)(p >> 16);
    }
    FENCE();
    bf16x8 ah2 = *reinterpret_cast<const bf16x8*>(&sby[tile0 + col][kg * 8]);
    f32x4 x3f = mm(ah2, Bf3, zero4);
#pragma unroll
    for (int reg = 0; reg < 4; reg++) {
      long grow = row0 + tile0 + kg * 4 + reg;
      out[grow * 16 + col] = xres[reg] + x3f[reg] + b3c;
    }
  }
}

extern "C" void kernel_launch(void* const* d_in, const int* in_sizes, int n_in,
                              void* d_out, int out_size, void* d_ws,
                              size_t ws_size, hipStream_t stream) {
  const float* x = (const float*)d_in[0];
  const float* rms1w = (const float*)d_in[1];
  const float* ipw = (const float*)d_in[2];
  const float* cw = (const float*)d_in[3];
  const float* cb = (const float*)d_in[4];
  const float* xpw = (const float*)d_in[5];
  const float* dtw = (const float*)d_in[6];
  const float* dtb = (const float*)d_in[7];
  const float* A_log = (const float*)d_in[8];
  const float* Dskip = (const float*)d_in[9];
  const float* opw = (const float*)d_in[10];
  const float* rms2w = (const float*)d_in[11];
  const float* f1w = (const float*)d_in[12];
  const float* f1b = (const float*)d_in[13];
  const float* f2w = (const float*)d_in[14];
  const float* f2b = (const float*)d_in[15];
  const float* f3w = (const float*)d_in[16];
  const float* f3b = (const float*)d_in[17];
  float* out = (float*)d_out;

  unsigned* rec = (unsigned*)d_ws;                     // 13.1 MiB
  float* Pb = (float*)(rec + (size_t)NCHT * RECU);     // 8 MiB
  float* Hb = Pb + SUMN;                               // 8 MiB
  float* segP = Hb + SUMN;                             // 256 KiB
  float* segH = segP + NBAT * NSEG * 512;              // 256 KiB
  float* carry = segH + NBAT * NSEG * 512;             // 256 KiB

  hipLaunchKernelGGL(k_prep, dim3(NCHT), dim3(128), 0, stream, x, rms1w, ipw,
                     cw, cb, xpw, dtw, dtb, A_log, Dskip, rec, Pb, Hb);
  hipLaunchKernelGGL(k_seg, dim3(256), dim3(256), 0, stream, Pb, Hb, segP,
                     segH);
  hipLaunchKernelGGL(k_carry, dim3(32), dim3(256), 0, stream, segP, segH,
                     carry);
  hipLaunchKernelGGL(k_mlp, dim3(NCHT), dim3(128), 0, stream, rec, x, A_log,
                     Pb, Hb, carry, dtw, dtb, rms1w, ipw, opw, rms2w, f1w, f1b,
                     f2w, f2b, f3w, f3b, out);
}

// Round 17
// 76.857 us; speedup vs baseline: 1.1913x; 1.1913x over previous
//
#include <hip/hip_runtime.h>

#define LSEQ 8192
#define NBAT 16
#define DMOD 16
#define DINN 32
#define DSTA 16
#define CL   32
#define NCH  (LSEQ / CL)            // 256 chunks per batch
#define NCHT (NBAT * NCH)           // 4096
#define NROWS (NBAT * LSEQ)         // 131072
#define SUMN ((size_t)NCHT * 512)
#define NSEG 8
#define SEGC (NCH / NSEG)           // 32
#define RECU 800                    // u32 per chunk: y-pairs[16] C-pairs[8] p0[1] x32
#define LOG2E 1.44269504f
#define FENCE() asm volatile("" ::: "memory")

typedef __attribute__((ext_vector_type(8))) short bf16x8;
typedef __attribute__((ext_vector_type(4))) float f32x4;

__device__ __forceinline__ float fsilu(float v) { return v / (1.f + __expf(-v)); }
__device__ __forceinline__ float fsoftplus(float v) {
  return v > 20.f ? v : __logf(1.f + __expf(v));
}
__device__ __forceinline__ unsigned packbf(float a, float b) {
  unsigned r;
  asm("v_cvt_pk_bf16_f32 %0, %1, %2" : "=v"(r) : "v"(a), "v"(b));
  return r;
}
__device__ __forceinline__ short f2bf(float f) {
  return (short)(packbf(f, f) & 0xffffu);
}
__device__ __forceinline__ float bf2f(short s) {
  union { unsigned u; float f; } v;
  v.u = ((unsigned)(unsigned short)s) << 16;
  return v.f;
}
__device__ __forceinline__ float bflo(unsigned u) {
  union { unsigned a; float f; } v; v.a = u << 16; return v.f;
}
__device__ __forceinline__ float bfhi(unsigned u) {
  union { unsigned a; float f; } v; v.a = u & 0xffff0000u; return v.f;
}

__device__ __forceinline__ void load_x_row(const float* __restrict__ x, long r,
                                           float* __restrict__ xr) {
  const float4* xp = reinterpret_cast<const float4*>(x + r * DMOD);
  float4 v0 = xp[0], v1 = xp[1], v2 = xp[2], v3 = xp[3];
  xr[0] = v0.x; xr[1] = v0.y; xr[2] = v0.z; xr[3] = v0.w;
  xr[4] = v1.x; xr[5] = v1.y; xr[6] = v1.z; xr[7] = v1.w;
  xr[8] = v2.x; xr[9] = v2.y; xr[10] = v2.z; xr[11] = v2.w;
  xr[12] = v3.x; xr[13] = v3.y; xr[14] = v3.z; xr[15] = v3.w;
}

__device__ __forceinline__ f32x4 mm(bf16x8 a, bf16x8 b, f32x4 c) {
  return __builtin_amdgcn_mfma_f32_16x16x32_bf16(a, b, c, 0, 0, 0);
}
__device__ __forceinline__ bf16x8 bfrag(const float* __restrict__ W, int ldw,
                                        int coloff, int col, int kg, int kreal) {
  bf16x8 b = {0, 0, 0, 0, 0, 0, 0, 0};
#pragma unroll
  for (int e = 0; e < 8; e++) {
    int k = kg * 8 + e;
    if (k < kreal) b[e] = f2bf(W[k * ldw + coloff + col]);
  }
  return b;
}

// ---- K1: wave-private prep + local scan. 1 wave = 1 chunk (32 rows).
// 256 thr = 4 chunks/block, grid 1024.  ZERO block barriers (intra-wave
// ordering via in-order DS pipeline + compile-time fences).
__global__ __launch_bounds__(256) void k_prep(
    const float* __restrict__ x, const float* __restrict__ rms1w,
    const float* __restrict__ ipw, const float* __restrict__ cw,
    const float* __restrict__ cb, const float* __restrict__ xpw,
    const float* __restrict__ dtw, const float* __restrict__ dtb,
    const float* __restrict__ A_log, const float* __restrict__ Dskip,
    unsigned* __restrict__ rec, float* __restrict__ Pb,
    float* __restrict__ Hb) {
  __shared__ short XM[4][35][36];  // xm bf16 (3 halo + 32); later prj B/C/p0
  __shared__ short X0[4][32][32];  // x0 bf16 cols 0..15; later dt bf16 cols 0..31
  __shared__ short XC[4][32][40];  // xc bf16 cols 0..31; y overwrites in F
  int t = threadIdx.x;
  int l = t & 63, wid = t >> 6;
  int col = l & 15, kg = l >> 4;
  int chunk = blockIdx.x * 4 + wid;
  long row0 = (long)chunk * CL;
  bool first = (chunk & (NCH - 1)) == 0;
  const f32x4 zero4 = {0.f, 0.f, 0.f, 0.f};

  bf16x8 Bip0 = bfrag(ipw, 64, 0, col, kg, 16);
  bf16x8 Bip1 = bfrag(ipw, 64, 16, col, kg, 16);
  bf16x8 Bdt, Bb, Bc;
#pragma unroll
  for (int e = 0; e < 8; e++) {
    int k = kg * 8 + e;
    Bdt[e] = (col == 0) ? f2bf(xpw[k * 33]) : (short)0;
    Bb[e] = f2bf(xpw[k * 33 + 1 + col]);
    Bc[e] = f2bf(xpw[k * 33 + 17 + col]);
  }

  // Phase A: rmsnorm -> x0 bf16 (2 lanes/row)
  {
    int row = l >> 1, hf = l & 1;
    const float4* xp =
        reinterpret_cast<const float4*>(x + (row0 + row) * DMOD + hf * 8);
    float4 v0 = xp[0], v1 = xp[1];
    float xr[8] = {v0.x, v0.y, v0.z, v0.w, v1.x, v1.y, v1.z, v1.w};
    float ss = 0.f;
#pragma unroll
    for (int i = 0; i < 8; i++) ss += xr[i] * xr[i];
    ss += __shfl_xor(ss, 1);
    float inv1 = rsqrtf(ss * (1.f / 16.f) + 1e-6f);
    unsigned u[4];
#pragma unroll
    for (int i = 0; i < 4; i++)
      u[i] = packbf(xr[2 * i] * inv1 * rms1w[hf * 8 + 2 * i],
                    xr[2 * i + 1] * inv1 * rms1w[hf * 8 + 2 * i + 1]);
    *reinterpret_cast<uint4*>(&X0[wid][row][hf * 8]) =
        make_uint4(u[0], u[1], u[2], u[3]);
  }
  // halo xm: lanes 0..47, lane -> (h = l>>4, cols k2, k2+1)
  if (l < 48) {
    int h = l >> 4, k2 = (l & 15) * 2;
    float a0 = 0.f, a1 = 0.f;
    if (!first) {
      float xr[16];
      load_x_row(x, row0 - 3 + h, xr);
      float ss = 0.f;
#pragma unroll
      for (int i = 0; i < 16; i++) ss += xr[i] * xr[i];
      float inv1 = rsqrtf(ss * (1.f / 16.f) + 1e-6f);
#pragma unroll
      for (int i = 0; i < 16; i++) {
        float x0i = xr[i] * inv1 * rms1w[i];
        a0 = fmaf(x0i, ipw[i * 64 + k2], a0);
        a1 = fmaf(x0i, ipw[i * 64 + k2 + 1], a1);
      }
    }
    *reinterpret_cast<unsigned*>(&XM[wid][h][k2]) = packbf(a0, a1);
  }
  FENCE();

  // Phase B: xm = x0 @ ipw[:, 0:32]; 2 tiles
#pragma unroll
  for (int rt = 0; rt < 2; rt++) {
    int arow = rt * 16 + col;
    bf16x8 a = {0, 0, 0, 0, 0, 0, 0, 0};
    if (kg < 2) a = *reinterpret_cast<const bf16x8*>(&X0[wid][arow][kg * 8]);
    f32x4 m0 = mm(a, Bip0, zero4);
    f32x4 m1 = mm(a, Bip1, zero4);
    int orow = 3 + rt * 16 + kg * 4;
#pragma unroll
    for (int reg = 0; reg < 4; reg++) {
      unsigned p = packbf(m0[reg], m1[reg]);
      XM[wid][orow + reg][col] = (short)(p & 0xffffu);
      XM[wid][orow + reg][col + 16] = (short)(p >> 16);
    }
  }
  FENCE();

  // Phase C: causal conv + silu (2 lanes/row, 16 d's each)
  {
    int row = l >> 1, hf = l & 1;
    unsigned u[8];
#pragma unroll
    for (int dp = 0; dp < 8; dp++) {
      int d = hf * 16 + dp * 2;
      float ce = cb[d], co = cb[d + 1];
#pragma unroll
      for (int k = 0; k < 4; k++) {
        unsigned xu = *reinterpret_cast<const unsigned*>(&XM[wid][row + k][d]);
        ce = fmaf(cw[d * 4 + k], bflo(xu), ce);
        co = fmaf(cw[(d + 1) * 4 + k], bfhi(xu), co);
      }
      u[dp] = packbf(fsilu(ce), fsilu(co));
    }
    *reinterpret_cast<uint4*>(&XC[wid][row][hf * 16]) =
        make_uint4(u[0], u[1], u[2], u[3]);
    *reinterpret_cast<uint4*>(&XC[wid][row][hf * 16 + 8]) =
        make_uint4(u[4], u[5], u[6], u[7]);
  }
  FENCE();

  // Phase D: proj MFMA -> prj into XM rows 3..34 (B 0..15, C 16..31, p0 @32)
#pragma unroll
  for (int rt = 0; rt < 2; rt++) {
    int arow = rt * 16 + col;
    bf16x8 a2 = *reinterpret_cast<const bf16x8*>(&XC[wid][arow][kg * 8]);
    f32x4 pd = mm(a2, Bdt, zero4);
    f32x4 pb = mm(a2, Bb, zero4);
    f32x4 pc = mm(a2, Bc, zero4);
    int orow = 3 + rt * 16 + kg * 4;
#pragma unroll
    for (int reg = 0; reg < 4; reg++) {
      unsigned p = packbf(pb[reg], pc[reg]);
      XM[wid][orow + reg][col] = (short)(p & 0xffffu);
      XM[wid][orow + reg][16 + col] = (short)(p >> 16);
      if (col == 0) XM[wid][orow + reg][32] = f2bf(pd[reg]);
    }
  }
  FENCE();

  // Phase D2: dt = softplus(p0*dtw+dtb) -> X0 cols 0..31 (x0 is dead)
  {
    int row = l >> 1, hf = l & 1;
    float p0 = bf2f(XM[wid][3 + row][32]);
    unsigned u[8];
#pragma unroll
    for (int dp = 0; dp < 8; dp++) {
      int d = hf * 16 + dp * 2;
      u[dp] = packbf(fsoftplus(fmaf(p0, dtw[d], dtb[d])),
                     fsoftplus(fmaf(p0, dtw[d + 1], dtb[d + 1])));
    }
    *reinterpret_cast<uint4*>(&X0[wid][row][hf * 16]) =
        make_uint4(u[0], u[1], u[2], u[3]);
    *reinterpret_cast<uint4*>(&X0[wid][row][hf * 16 + 8]) =
        make_uint4(u[4], u[5], u[6], u[7]);
  }
  FENCE();

  // Phase F: scan; lane -> (d = l>>1, 8 states sh..sh+7)
  {
    int d = l >> 1, sh = (l & 1) * 8;
    float4 alo = *reinterpret_cast<const float4*>(A_log + d * DSTA + sh);
    float4 ahi = *reinterpret_cast<const float4*>(A_log + d * DSTA + sh + 4);
    float Ad[8] = {-__expf(alo.x) * LOG2E, -__expf(alo.y) * LOG2E,
                   -__expf(alo.z) * LOG2E, -__expf(alo.w) * LOG2E,
                   -__expf(ahi.x) * LOG2E, -__expf(ahi.y) * LOG2E,
                   -__expf(ahi.z) * LOG2E, -__expf(ahi.w) * LOG2E};
    float dskd = Dskip[d];
    float H[8] = {0.f, 0.f, 0.f, 0.f, 0.f, 0.f, 0.f, 0.f};
    float cum = 0.f;
    bool wy = (l & 1) == 0;
#pragma unroll 4
    for (int li = 0; li < CL; li++) {
      float dt = bf2f(X0[wid][li][d]);
      float xcv = bf2f(XC[wid][li][d]);
      float dx = dt * xcv;
      cum += dt;
      uint2 bu0 = *reinterpret_cast<const uint2*>(&XM[wid][3 + li][sh]);
      uint2 bu1 = *reinterpret_cast<const uint2*>(&XM[wid][3 + li][sh + 4]);
      uint2 cu0 = *reinterpret_cast<const uint2*>(&XM[wid][3 + li][16 + sh]);
      uint2 cu1 = *reinterpret_cast<const uint2*>(&XM[wid][3 + li][16 + sh + 4]);
      float a;
      a = __builtin_amdgcn_exp2f(dt * Ad[0]); H[0] = fmaf(a, H[0], dx * bflo(bu0.x));
      a = __builtin_amdgcn_exp2f(dt * Ad[1]); H[1] = fmaf(a, H[1], dx * bfhi(bu0.x));
      a = __builtin_amdgcn_exp2f(dt * Ad[2]); H[2] = fmaf(a, H[2], dx * bflo(bu0.y));
      a = __builtin_amdgcn_exp2f(dt * Ad[3]); H[3] = fmaf(a, H[3], dx * bfhi(bu0.y));
      a = __builtin_amdgcn_exp2f(dt * Ad[4]); H[4] = fmaf(a, H[4], dx * bflo(bu1.x));
      a = __builtin_amdgcn_exp2f(dt * Ad[5]); H[5] = fmaf(a, H[5], dx * bfhi(bu1.x));
      a = __builtin_amdgcn_exp2f(dt * Ad[6]); H[6] = fmaf(a, H[6], dx * bflo(bu1.y));
      a = __builtin_amdgcn_exp2f(dt * Ad[7]); H[7] = fmaf(a, H[7], dx * bfhi(bu1.y));
      float y = bflo(cu0.x) * H[0];
      y = fmaf(bfhi(cu0.x), H[1], y);
      y = fmaf(bflo(cu0.y), H[2], y);
      y = fmaf(bfhi(cu0.y), H[3], y);
      y = fmaf(bflo(cu1.x), H[4], y);
      y = fmaf(bfhi(cu1.x), H[5], y);
      y = fmaf(bflo(cu1.y), H[6], y);
      y = fmaf(bfhi(cu1.y), H[7], y);
      y += __shfl_xor(y, 1);
      if (wy) XC[wid][li][d] = f2bf(fmaf(dskd, xcv, y));
    }
    size_t sb_ = (size_t)chunk * 512 + (size_t)(l * 8);
    *reinterpret_cast<float4*>(Pb + sb_) = make_float4(
        __builtin_amdgcn_exp2f(cum * Ad[0]), __builtin_amdgcn_exp2f(cum * Ad[1]),
        __builtin_amdgcn_exp2f(cum * Ad[2]), __builtin_amdgcn_exp2f(cum * Ad[3]));
    *reinterpret_cast<float4*>(Pb + sb_ + 4) = make_float4(
        __builtin_amdgcn_exp2f(cum * Ad[4]), __builtin_amdgcn_exp2f(cum * Ad[5]),
        __builtin_amdgcn_exp2f(cum * Ad[6]), __builtin_amdgcn_exp2f(cum * Ad[7]));
    *reinterpret_cast<float4*>(Hb + sb_) = make_float4(H[0], H[1], H[2], H[3]);
    *reinterpret_cast<float4*>(Hb + sb_ + 4) = make_float4(H[4], H[5], H[6], H[7]);
  }
  FENCE();

  // Phase G: record writes (wave-private, coalesced)
  {
    unsigned* rb = rec + (size_t)chunk * RECU;
#pragma unroll
    for (int i = 0; i < 13; i++) {
      int idx = i * 64 + l;
      if (idx < 800) {
        int c = idx >> 5, r = idx & 31;
        unsigned val;
        if (c < 16)
          val = *reinterpret_cast<const unsigned*>(&XC[wid][r][2 * c]);
        else if (c < 24)
          val = *reinterpret_cast<const unsigned*>(
              &XM[wid][3 + r][16 + 2 * (c - 16)]);
        else
          val = (unsigned)(unsigned short)XM[wid][3 + r][32];
        rb[idx] = val;
      }
    }
  }
}

// ---- K2a: segmented exclusive scan IN PLACE + segment summaries
__global__ __launch_bounds__(256) void k_seg(float* __restrict__ Pb,
                                             float* __restrict__ Hb,
                                             float* __restrict__ segP,
                                             float* __restrict__ segH) {
  int g = blockIdx.x * 256 + threadIdx.x;  // 65536
  int b = g >> 12;
  int rem = g & 4095;
  int seg = rem >> 9, st = rem & 511;
  size_t o = ((size_t)(b * NCH + seg * SEGC)) * 512 + st;
  float h = 0.f, p = 1.f;
#pragma unroll 4
  for (int c = 0; c < SEGC; c++) {
    float P = Pb[o], H = Hb[o];
    Pb[o] = p;
    Hb[o] = h;
    h = fmaf(P, h, H);
    p *= P;
    o += 512;
  }
  size_t so = (size_t)(b * NSEG + seg) * 512 + st;
  segP[so] = p;
  segH[so] = h;
}

// ---- K2b: scan over segment summaries -> segment start states
__global__ __launch_bounds__(256) void k_carry(const float* __restrict__ segP,
                                               const float* __restrict__ segH,
                                               float* __restrict__ carry) {
  int g = blockIdx.x * 256 + threadIdx.x;  // 8192
  int b = g >> 9, st = g & 511;
  float h = 0.f;
#pragma unroll
  for (int s = 0; s < NSEG; s++) {
    size_t so = (size_t)(b * NSEG + s) * 512 + st;
    carry[so] = h;
    h = fmaf(segP[so], h, segH[so]);
  }
}

// ---- K3: wave-private h0-correction + MFMA epilogue. 1 wave = 1 chunk.
// 256 thr = 4 chunks/block, grid 1024.  ONE barrier (Ads table).
__global__ __launch_bounds__(256) void k_mlp(
    const unsigned* __restrict__ rec, const float* __restrict__ x,
    const float* __restrict__ A_log, const float* __restrict__ Pb,
    const float* __restrict__ Hb, const float* __restrict__ carry,
    const float* __restrict__ dtw, const float* __restrict__ dtb,
    const float* __restrict__ rms1w, const float* __restrict__ ipw,
    const float* __restrict__ opw, const float* __restrict__ rms2w,
    const float* __restrict__ f1w, const float* __restrict__ f1b,
    const float* __restrict__ f2w, const float* __restrict__ f2b,
    const float* __restrict__ f3w, const float* __restrict__ f3b,
    float* __restrict__ out) {
  __shared__ float Ads[512];       // block-shared, pre-scaled by LOG2E
  __shared__ float h0w[4][512];    // wave-private h0
  __shared__ short sbx[4][32][24]; // x0 bf16
  __shared__ short sby[4][32][40]; // yfin -> yo -> x2 -> h1 -> h2 (bf16)
  int t = threadIdx.x;
  int l = t & 63, wid = t >> 6;
  int gc = blockIdx.x * 4 + wid;
  long row0 = (long)gc * CL;

  Ads[t] = -__expf(A_log[t]) * LOG2E;
  Ads[256 + t] = -__expf(A_log[256 + t]) * LOG2E;
  // h0 for this wave's chunk (8 states/lane)
  {
    size_t o = (size_t)gc * 512 + (size_t)(l * 8);
    int b = gc >> 8, seg = (gc >> 5) & 7;
    size_t co = (size_t)(b * NSEG + seg) * 512 + (size_t)(l * 8);
    float4 pv0 = *reinterpret_cast<const float4*>(Pb + o);
    float4 pv1 = *reinterpret_cast<const float4*>(Pb + o + 4);
    float4 hv0 = *reinterpret_cast<const float4*>(Hb + o);
    float4 hv1 = *reinterpret_cast<const float4*>(Hb + o + 4);
    float4 cv0 = *reinterpret_cast<const float4*>(carry + co);
    float4 cv1 = *reinterpret_cast<const float4*>(carry + co + 4);
    *reinterpret_cast<float4*>(&h0w[wid][l * 8]) =
        make_float4(fmaf(pv0.x, cv0.x, hv0.x), fmaf(pv0.y, cv0.y, hv0.y),
                    fmaf(pv0.z, cv0.z, hv0.z), fmaf(pv0.w, cv0.w, hv0.w));
    *reinterpret_cast<float4*>(&h0w[wid][l * 8 + 4]) =
        make_float4(fmaf(pv1.x, cv1.x, hv1.x), fmaf(pv1.y, cv1.y, hv1.y),
                    fmaf(pv1.z, cv1.z, hv1.z), fmaf(pv1.w, cv1.w, hv1.w));
  }
  // rmsnorm -> x0 bf16 (2 lanes/row)
  {
    int row = l >> 1, hf = l & 1;
    const float4* xp =
        reinterpret_cast<const float4*>(x + (row0 + row) * DMOD + hf * 8);
    float4 v0 = xp[0], v1 = xp[1];
    float xr[8] = {v0.x, v0.y, v0.z, v0.w, v1.x, v1.y, v1.z, v1.w};
    float ss = 0.f;
#pragma unroll
    for (int i = 0; i < 8; i++) ss += xr[i] * xr[i];
    ss += __shfl_xor(ss, 1);
    float inv1 = rsqrtf(ss * (1.f / 16.f) + 1e-6f);
    unsigned u[4];
#pragma unroll
    for (int i = 0; i < 4; i++)
      u[i] = packbf(xr[2 * i] * inv1 * rms1w[hf * 8 + 2 * i],
                    xr[2 * i + 1] * inv1 * rms1w[hf * 8 + 2 * i + 1]);
    *reinterpret_cast<uint4*>(&sbx[wid][row][hf * 8]) =
        make_uint4(u[0], u[1], u[2], u[3]);
  }
  __syncthreads();  // Ads table (block-shared)

  // correction: yfin = ypre + sum_s exp2(Ads*cumdt)*C*h0   (wave-private)
  {
    int half = l >> 5, r = l & 31;
    const unsigned* rb = rec + (size_t)gc * RECU;
    float Cv[16];
#pragma unroll
    for (int c = 0; c < 8; c++) {
      unsigned u = rb[(16 + c) * 32 + r];
      Cv[2 * c] = bflo(u);
      Cv[2 * c + 1] = bfhi(u);
    }
    float p0 = bflo(rb[24 * 32 + r]);
    const float* h0c = h0w[wid];
#pragma unroll
    for (int cc = 0; cc < 8; cc++) {
      int c = half * 8 + cc;
      int d0 = 2 * c, d1 = 2 * c + 1;
      float cd0 = fsoftplus(fmaf(p0, dtw[d0], dtb[d0]));
      float cd1 = fsoftplus(fmaf(p0, dtw[d1], dtb[d1]));
#pragma unroll
      for (int dl = 1; dl < 32; dl <<= 1) {
        float u0 = __shfl_up(cd0, dl, 32);
        float u1 = __shfl_up(cd1, dl, 32);
        if (r >= dl) { cd0 += u0; cd1 += u1; }
      }
      unsigned yu = rb[c * 32 + r];
      float acc0 = bflo(yu), acc1 = bfhi(yu);
      int dof0 = d0 * 16, dof1 = d1 * 16;
#pragma unroll
      for (int s = 0; s < 16; s++) {
        float e0 = __builtin_amdgcn_exp2f(Ads[dof0 + s] * cd0);
        float e1 = __builtin_amdgcn_exp2f(Ads[dof1 + s] * cd1);
        acc0 = fmaf(e0 * Cv[s], h0c[dof0 + s], acc0);
        acc1 = fmaf(e1 * Cv[s], h0c[dof1 + s], acc1);
      }
      *reinterpret_cast<unsigned*>(&sby[wid][r][2 * c]) = packbf(acc0, acc1);
    }
  }
  FENCE();

  // MFMA epilogue: this wave's 32 rows (2 tiles)
  {
    int col = l & 15, kg = l >> 4;
    bf16x8 Bz0 = bfrag(ipw + 32, 64, 0, col, kg, 16);
    bf16x8 Bz1 = bfrag(ipw + 32, 64, 16, col, kg, 16);
    bf16x8 Bop = bfrag(opw, 16, 0, col, kg, 32);
    bf16x8 Bf1_0 = bfrag(f1w, 32, 0, col, kg, 16);
    bf16x8 Bf1_1 = bfrag(f1w, 32, 16, col, kg, 16);
    bf16x8 Bf2_0 = bfrag(f2w, 32, 0, col, kg, 32);
    bf16x8 Bf2_1 = bfrag(f2w, 32, 16, col, kg, 32);
    bf16x8 Bf3 = bfrag(f3w, 16, 0, col, kg, 32);
    float b1_0 = f1b[col], b1_1 = f1b[16 + col];
    float b2_0 = f2b[col], b2_1 = f2b[16 + col];
    float b3c = f3b[col], rw2 = rms2w[col];
    const f32x4 zero4 = {0.f, 0.f, 0.f, 0.f};
#pragma unroll 1
    for (int rt = 0; rt < 2; rt++) {
      int tile0 = rt * 16;
      bf16x8 ax0 = {0, 0, 0, 0, 0, 0, 0, 0};
      if (kg < 2)
        ax0 = *reinterpret_cast<const bf16x8*>(&sbx[wid][tile0 + col][kg * 8]);
      f32x4 zf0 = mm(ax0, Bz0, zero4);
      f32x4 zf1 = mm(ax0, Bz1, zero4);
#pragma unroll
      for (int reg = 0; reg < 4; reg++) {
        int lrow = tile0 + kg * 4 + reg;
        float y0 = bf2f(sby[wid][lrow][col]);
        float y1 = bf2f(sby[wid][lrow][16 + col]);
        unsigned p = packbf(y0 * fsilu(zf0[reg]), y1 * fsilu(zf1[reg]));
        sby[wid][lrow][col] = (short)(p & 0xffffu);
        sby[wid][lrow][16 + col] = (short)(p >> 16);
      }
      FENCE();
      bf16x8 ayo =
          *reinterpret_cast<const bf16x8*>(&sby[wid][tile0 + col][kg * 8]);
      f32x4 x1f = mm(ayo, Bop, zero4);
      float xres[4];
#pragma unroll
      for (int reg = 0; reg < 4; reg++) {
        long grow = row0 + tile0 + kg * 4 + reg;
        xres[reg] = x1f[reg] + x[grow * 16 + col];
      }
#pragma unroll
      for (int reg = 0; reg < 4; reg++) {
        float ss = xres[reg] * xres[reg];
        ss += __shfl_xor(ss, 1);
        ss += __shfl_xor(ss, 2);
        ss += __shfl_xor(ss, 4);
        ss += __shfl_xor(ss, 8);
        float inv2 = rsqrtf(ss * (1.f / 16.f) + 1e-6f);
        sby[wid][tile0 + kg * 4 + reg][col] = f2bf(xres[reg] * inv2 * rw2);
      }
      FENCE();
      bf16x8 ax2 = {0, 0, 0, 0, 0, 0, 0, 0};
      if (kg < 2)
        ax2 = *reinterpret_cast<const bf16x8*>(&sby[wid][tile0 + col][kg * 8]);
      f32x4 h1f0 = mm(ax2, Bf1_0, zero4);
      f32x4 h1f1 = mm(ax2, Bf1_1, zero4);
#pragma unroll
      for (int reg = 0; reg < 4; reg++) {
        int lrow = tile0 + kg * 4 + reg;
        unsigned p = packbf(fmaxf(h1f0[reg] + b1_0, 0.f),
                            fmaxf(h1f1[reg] + b1_1, 0.f));
        sby[wid][lrow][col] = (short)(p & 0xffffu);
        sby[wid][lrow][16 + col] = (short)(p >> 16);
      }
      FENCE();
      bf16x8 ah1 =
          *reinterpret_cast<const bf16x8*>(&sby[wid][tile0 + col][kg * 8]);
      f32x4 h2f0 = mm(ah1, Bf2_0, zero4);
      f32x4 h2f1 = mm(ah1, Bf2_1, zero4);
#pragma unroll
      for (int reg = 0; reg < 4; reg++) {
        int lrow = tile0 + kg * 4 + reg;
        unsigned p = packbf(fmaxf(h2f0[reg] + b2_0, 0.f),
                            fmaxf(h2f1[reg] + b2_1, 0.f));
        sby[wid][lrow][col] = (short)(p & 0xffffu);
        sby[wid][lrow][16 + col] = (short)(p >> 16);
      }
      FENCE();
      bf16x8 ah2 =
          *reinterpret_cast<const bf16x8*>(&sby[wid][tile0 + col][kg * 8]);
      f32x4 x3f = mm(ah2, Bf3, zero4);
#pragma unroll
      for (int reg = 0; reg < 4; reg++) {
        long grow = row0 + tile0 + kg * 4 + reg;
        out[grow * 16 + col] = xres[reg] + x3f[reg] + b3c;
      }
      FENCE();
    }
  }
}

extern "C" void kernel_launch(void* const* d_in, const int* in_sizes, int n_in,
                              void* d_out, int out_size, void* d_ws,
                              size_t ws_size, hipStream_t stream) {
  const float* x = (const float*)d_in[0];
  const float* rms1w = (const float*)d_in[1];
  const float* ipw = (const float*)d_in[2];
  const float* cw = (const float*)d_in[3];
  const float* cb = (const float*)d_in[4];
  const float* xpw = (const float*)d_in[5];
  const float* dtw = (const float*)d_in[6];
  const float* dtb = (const float*)d_in[7];
  const float* A_log = (const float*)d_in[8];
  const float* Dskip = (const float*)d_in[9];
  const float* opw = (const float*)d_in[10];
  const float* rms2w = (const float*)d_in[11];
  const float* f1w = (const float*)d_in[12];
  const float* f1b = (const float*)d_in[13];
  const float* f2w = (const float*)d_in[14];
  const float* f2b = (const float*)d_in[15];
  const float* f3w = (const float*)d_in[16];
  const float* f3b = (const float*)d_in[17];
  float* out = (float*)d_out;

  unsigned* rec = (unsigned*)d_ws;                     // 13.1 MiB
  float* Pb = (float*)(rec + (size_t)NCHT * RECU);     // 8 MiB
  float* Hb = Pb + SUMN;                               // 8 MiB
  float* segP = Hb + SUMN;                             // 256 KiB
  float* segH = segP + NBAT * NSEG * 512;              // 256 KiB
  float* carry = segH + NBAT * NSEG * 512;             // 256 KiB

  hipLaunchKernelGGL(k_prep, dim3(NROWS / 128), dim3(256), 0, stream, x, rms1w,
                     ipw, cw, cb, xpw, dtw, dtb, A_log, Dskip, rec, Pb, Hb);
  hipLaunchKernelGGL(k_seg, dim3(256), dim3(256), 0, stream, Pb, Hb, segP,
                     segH);
  hipLaunchKernelGGL(k_carry, dim3(32), dim3(256), 0, stream, segP, segH,
                     carry);
  hipLaunchKernelGGL(k_mlp, dim3(NROWS / 128), dim3(256), 0, stream, rec, x,
                     A_log, Pb, Hb, carry, dtw, dtb, rms1w, ipw, opw, rms2w,
                     f1w, f1b, f2w, f2b, f3w, f3b, out);
}

// Round 18
// 74.941 us; speedup vs baseline: 1.2217x; 1.0256x over previous
//
#include <hip/hip_runtime.h>

#define LSEQ 8192
#define NBAT 16
#define DMOD 16
#define DINN 32
#define DSTA 16
#define CL   32
#define NCH  (LSEQ / CL)            // 256 chunks per batch
#define NCHT (NBAT * NCH)           // 4096
#define NROWS (NBAT * LSEQ)         // 131072
#define SUMN ((size_t)NCHT * 512)
#define NSEG 8
#define SEGC (NCH / NSEG)           // 32
#define RECU 800                    // u32 per chunk: y-pairs[16] C-pairs[8] p0[1] x32
#define LOG2E 1.44269504f
#define FENCE() asm volatile("" ::: "memory")

typedef __attribute__((ext_vector_type(8))) short bf16x8;
typedef __attribute__((ext_vector_type(4))) float f32x4;

__device__ __forceinline__ float fsilu(float v) { return v / (1.f + __expf(-v)); }
__device__ __forceinline__ float fsoftplus(float v) {
  return v > 20.f ? v : __logf(1.f + __expf(v));
}
__device__ __forceinline__ unsigned packbf(float a, float b) {
  unsigned r;
  asm("v_cvt_pk_bf16_f32 %0, %1, %2" : "=v"(r) : "v"(a), "v"(b));
  return r;
}
__device__ __forceinline__ short f2bf(float f) {
  return (short)(packbf(f, f) & 0xffffu);
}
__device__ __forceinline__ float bf2f(short s) {
  union { unsigned u; float f; } v;
  v.u = ((unsigned)(unsigned short)s) << 16;
  return v.f;
}
__device__ __forceinline__ float bflo(unsigned u) {
  union { unsigned a; float f; } v; v.a = u << 16; return v.f;
}
__device__ __forceinline__ float bfhi(unsigned u) {
  union { unsigned a; float f; } v; v.a = u & 0xffff0000u; return v.f;
}

__device__ __forceinline__ void load_x_row(const float* __restrict__ x, long r,
                                           float* __restrict__ xr) {
  const float4* xp = reinterpret_cast<const float4*>(x + r * DMOD);
  float4 v0 = xp[0], v1 = xp[1], v2 = xp[2], v3 = xp[3];
  xr[0] = v0.x; xr[1] = v0.y; xr[2] = v0.z; xr[3] = v0.w;
  xr[4] = v1.x; xr[5] = v1.y; xr[6] = v1.z; xr[7] = v1.w;
  xr[8] = v2.x; xr[9] = v2.y; xr[10] = v2.z; xr[11] = v2.w;
  xr[12] = v3.x; xr[13] = v3.y; xr[14] = v3.z; xr[15] = v3.w;
}

__device__ __forceinline__ f32x4 mm(bf16x8 a, bf16x8 b, f32x4 c) {
  return __builtin_amdgcn_mfma_f32_16x16x32_bf16(a, b, c, 0, 0, 0);
}
__device__ __forceinline__ bf16x8 bfrag(const float* __restrict__ W, int ldw,
                                        int coloff, int col, int kg, int kreal) {
  bf16x8 b = {0, 0, 0, 0, 0, 0, 0, 0};
#pragma unroll
  for (int e = 0; e < 8; e++) {
    int k = kg * 8 + e;
    if (k < kreal) b[e] = f2bf(W[k * ldw + coloff + col]);
  }
  return b;
}

// ---- K1: wave-private prep + local scan. 1 wave = 1 chunk (32 rows).
// 256 thr = 4 chunks/block, grid 1024.  ZERO block barriers.
__global__ __launch_bounds__(256) void k_prep(
    const float* __restrict__ x, const float* __restrict__ rms1w,
    const float* __restrict__ ipw, const float* __restrict__ cw,
    const float* __restrict__ cb, const float* __restrict__ xpw,
    const float* __restrict__ dtw, const float* __restrict__ dtb,
    const float* __restrict__ A_log, const float* __restrict__ Dskip,
    unsigned* __restrict__ rec, float* __restrict__ Pb,
    float* __restrict__ Hb) {
  __shared__ short XM[4][35][36];  // xm bf16 (3 halo + 32); later prj B/C/p0
  __shared__ short X0[4][32][32];  // x0 bf16 cols 0..15; later dt bf16 cols 0..31
  __shared__ short XC[4][32][40];  // xc bf16 cols 0..31; y overwrites in F
  int t = threadIdx.x;
  int l = t & 63, wid = t >> 6;
  int col = l & 15, kg = l >> 4;
  int chunk = blockIdx.x * 4 + wid;
  long row0 = (long)chunk * CL;
  bool first = (chunk & (NCH - 1)) == 0;
  const f32x4 zero4 = {0.f, 0.f, 0.f, 0.f};

  bf16x8 Bip0 = bfrag(ipw, 64, 0, col, kg, 16);
  bf16x8 Bip1 = bfrag(ipw, 64, 16, col, kg, 16);
  bf16x8 Bdt, Bb, Bc;
#pragma unroll
  for (int e = 0; e < 8; e++) {
    int k = kg * 8 + e;
    Bdt[e] = (col == 0) ? f2bf(xpw[k * 33]) : (short)0;
    Bb[e] = f2bf(xpw[k * 33 + 1 + col]);
    Bc[e] = f2bf(xpw[k * 33 + 17 + col]);
  }

  // Phase A: rmsnorm -> x0 bf16 (2 lanes/row)
  {
    int row = l >> 1, hf = l & 1;
    const float4* xp =
        reinterpret_cast<const float4*>(x + (row0 + row) * DMOD + hf * 8);
    float4 v0 = xp[0], v1 = xp[1];
    float xr[8] = {v0.x, v0.y, v0.z, v0.w, v1.x, v1.y, v1.z, v1.w};
    float ss = 0.f;
#pragma unroll
    for (int i = 0; i < 8; i++) ss += xr[i] * xr[i];
    ss += __shfl_xor(ss, 1);
    float inv1 = rsqrtf(ss * (1.f / 16.f) + 1e-6f);
    unsigned u[4];
#pragma unroll
    for (int i = 0; i < 4; i++)
      u[i] = packbf(xr[2 * i] * inv1 * rms1w[hf * 8 + 2 * i],
                    xr[2 * i + 1] * inv1 * rms1w[hf * 8 + 2 * i + 1]);
    *reinterpret_cast<uint4*>(&X0[wid][row][hf * 8]) =
        make_uint4(u[0], u[1], u[2], u[3]);
  }
  // halo xm: lanes 0..47, lane -> (h = l>>4, cols k2, k2+1)
  if (l < 48) {
    int h = l >> 4, k2 = (l & 15) * 2;
    float a0 = 0.f, a1 = 0.f;
    if (!first) {
      float xr[16];
      load_x_row(x, row0 - 3 + h, xr);
      float ss = 0.f;
#pragma unroll
      for (int i = 0; i < 16; i++) ss += xr[i] * xr[i];
      float inv1 = rsqrtf(ss * (1.f / 16.f) + 1e-6f);
#pragma unroll
      for (int i = 0; i < 16; i++) {
        float x0i = xr[i] * inv1 * rms1w[i];
        a0 = fmaf(x0i, ipw[i * 64 + k2], a0);
        a1 = fmaf(x0i, ipw[i * 64 + k2 + 1], a1);
      }
    }
    *reinterpret_cast<unsigned*>(&XM[wid][h][k2]) = packbf(a0, a1);
  }
  FENCE();

  // Phase B: xm = x0 @ ipw[:, 0:32]; 2 tiles
#pragma unroll
  for (int rt = 0; rt < 2; rt++) {
    int arow = rt * 16 + col;
    bf16x8 a = {0, 0, 0, 0, 0, 0, 0, 0};
    if (kg < 2) a = *reinterpret_cast<const bf16x8*>(&X0[wid][arow][kg * 8]);
    f32x4 m0 = mm(a, Bip0, zero4);
    f32x4 m1 = mm(a, Bip1, zero4);
    int orow = 3 + rt * 16 + kg * 4;
#pragma unroll
    for (int reg = 0; reg < 4; reg++) {
      unsigned p = packbf(m0[reg], m1[reg]);
      XM[wid][orow + reg][col] = (short)(p & 0xffffu);
      XM[wid][orow + reg][col + 16] = (short)(p >> 16);
    }
  }
  FENCE();

  // Phase C: causal conv + silu (2 lanes/row, 16 d's each)
  {
    int row = l >> 1, hf = l & 1;
    unsigned u[8];
#pragma unroll
    for (int dp = 0; dp < 8; dp++) {
      int d = hf * 16 + dp * 2;
      float ce = cb[d], co = cb[d + 1];
#pragma unroll
      for (int k = 0; k < 4; k++) {
        unsigned xu = *reinterpret_cast<const unsigned*>(&XM[wid][row + k][d]);
        ce = fmaf(cw[d * 4 + k], bflo(xu), ce);
        co = fmaf(cw[(d + 1) * 4 + k], bfhi(xu), co);
      }
      u[dp] = packbf(fsilu(ce), fsilu(co));
    }
    *reinterpret_cast<uint4*>(&XC[wid][row][hf * 16]) =
        make_uint4(u[0], u[1], u[2], u[3]);
    *reinterpret_cast<uint4*>(&XC[wid][row][hf * 16 + 8]) =
        make_uint4(u[4], u[5], u[6], u[7]);
  }
  FENCE();

  // Phase D: proj MFMA -> prj into XM rows 3..34 (B 0..15, C 16..31, p0 @32)
#pragma unroll
  for (int rt = 0; rt < 2; rt++) {
    int arow = rt * 16 + col;
    bf16x8 a2 = *reinterpret_cast<const bf16x8*>(&XC[wid][arow][kg * 8]);
    f32x4 pd = mm(a2, Bdt, zero4);
    f32x4 pb = mm(a2, Bb, zero4);
    f32x4 pc = mm(a2, Bc, zero4);
    int orow = 3 + rt * 16 + kg * 4;
#pragma unroll
    for (int reg = 0; reg < 4; reg++) {
      unsigned p = packbf(pb[reg], pc[reg]);
      XM[wid][orow + reg][col] = (short)(p & 0xffffu);
      XM[wid][orow + reg][16 + col] = (short)(p >> 16);
      if (col == 0) XM[wid][orow + reg][32] = f2bf(pd[reg]);
    }
  }
  FENCE();

  // Phase D2: dt = softplus(p0*dtw+dtb) -> X0 cols 0..31 (x0 is dead)
  {
    int row = l >> 1, hf = l & 1;
    float p0 = bf2f(XM[wid][3 + row][32]);
    unsigned u[8];
#pragma unroll
    for (int dp = 0; dp < 8; dp++) {
      int d = hf * 16 + dp * 2;
      u[dp] = packbf(fsoftplus(fmaf(p0, dtw[d], dtb[d])),
                     fsoftplus(fmaf(p0, dtw[d + 1], dtb[d + 1])));
    }
    *reinterpret_cast<uint4*>(&X0[wid][row][hf * 16]) =
        make_uint4(u[0], u[1], u[2], u[3]);
    *reinterpret_cast<uint4*>(&X0[wid][row][hf * 16 + 8]) =
        make_uint4(u[4], u[5], u[6], u[7]);
  }
  FENCE();

  // Phase F: scan; lane -> (d = l>>1, 8 states sh..sh+7)
  {
    int d = l >> 1, sh = (l & 1) * 8;
    float4 alo = *reinterpret_cast<const float4*>(A_log + d * DSTA + sh);
    float4 ahi = *reinterpret_cast<const float4*>(A_log + d * DSTA + sh + 4);
    float Ad[8] = {-__expf(alo.x) * LOG2E, -__expf(alo.y) * LOG2E,
                   -__expf(alo.z) * LOG2E, -__expf(alo.w) * LOG2E,
                   -__expf(ahi.x) * LOG2E, -__expf(ahi.y) * LOG2E,
                   -__expf(ahi.z) * LOG2E, -__expf(ahi.w) * LOG2E};
    float dskd = Dskip[d];
    float H[8] = {0.f, 0.f, 0.f, 0.f, 0.f, 0.f, 0.f, 0.f};
    float cum = 0.f;
    bool wy = (l & 1) == 0;
#pragma unroll 4
    for (int li = 0; li < CL; li++) {
      float dt = bf2f(X0[wid][li][d]);
      float xcv = bf2f(XC[wid][li][d]);
      float dx = dt * xcv;
      cum += dt;
      uint2 bu0 = *reinterpret_cast<const uint2*>(&XM[wid][3 + li][sh]);
      uint2 bu1 = *reinterpret_cast<const uint2*>(&XM[wid][3 + li][sh + 4]);
      uint2 cu0 = *reinterpret_cast<const uint2*>(&XM[wid][3 + li][16 + sh]);
      uint2 cu1 = *reinterpret_cast<const uint2*>(&XM[wid][3 + li][16 + sh + 4]);
      float a;
      a = __builtin_amdgcn_exp2f(dt * Ad[0]); H[0] = fmaf(a, H[0], dx * bflo(bu0.x));
      a = __builtin_amdgcn_exp2f(dt * Ad[1]); H[1] = fmaf(a, H[1], dx * bfhi(bu0.x));
      a = __builtin_amdgcn_exp2f(dt * Ad[2]); H[2] = fmaf(a, H[2], dx * bflo(bu0.y));
      a = __builtin_amdgcn_exp2f(dt * Ad[3]); H[3] = fmaf(a, H[3], dx * bfhi(bu0.y));
      a = __builtin_amdgcn_exp2f(dt * Ad[4]); H[4] = fmaf(a, H[4], dx * bflo(bu1.x));
      a = __builtin_amdgcn_exp2f(dt * Ad[5]); H[5] = fmaf(a, H[5], dx * bfhi(bu1.x));
      a = __builtin_amdgcn_exp2f(dt * Ad[6]); H[6] = fmaf(a, H[6], dx * bflo(bu1.y));
      a = __builtin_amdgcn_exp2f(dt * Ad[7]); H[7] = fmaf(a, H[7], dx * bfhi(bu1.y));
      float y = bflo(cu0.x) * H[0];
      y = fmaf(bfhi(cu0.x), H[1], y);
      y = fmaf(bflo(cu0.y), H[2], y);
      y = fmaf(bfhi(cu0.y), H[3], y);
      y = fmaf(bflo(cu1.x), H[4], y);
      y = fmaf(bfhi(cu1.x), H[5], y);
      y = fmaf(bflo(cu1.y), H[6], y);
      y = fmaf(bfhi(cu1.y), H[7], y);
      y += __shfl_xor(y, 1);
      if (wy) XC[wid][li][d] = f2bf(fmaf(dskd, xcv, y));
    }
    size_t sb_ = (size_t)chunk * 512 + (size_t)(l * 8);
    *reinterpret_cast<float4*>(Pb + sb_) = make_float4(
        __builtin_amdgcn_exp2f(cum * Ad[0]), __builtin_amdgcn_exp2f(cum * Ad[1]),
        __builtin_amdgcn_exp2f(cum * Ad[2]), __builtin_amdgcn_exp2f(cum * Ad[3]));
    *reinterpret_cast<float4*>(Pb + sb_ + 4) = make_float4(
        __builtin_amdgcn_exp2f(cum * Ad[4]), __builtin_amdgcn_exp2f(cum * Ad[5]),
        __builtin_amdgcn_exp2f(cum * Ad[6]), __builtin_amdgcn_exp2f(cum * Ad[7]));
    *reinterpret_cast<float4*>(Hb + sb_) = make_float4(H[0], H[1], H[2], H[3]);
    *reinterpret_cast<float4*>(Hb + sb_ + 4) = make_float4(H[4], H[5], H[6], H[7]);
  }
  FENCE();

  // Phase G: record writes (wave-private, coalesced)
  {
    unsigned* rb = rec + (size_t)chunk * RECU;
#pragma unroll
    for (int i = 0; i < 13; i++) {
      int idx = i * 64 + l;
      if (idx < 800) {
        int c = idx >> 5, r = idx & 31;
        unsigned val;
        if (c < 16)
          val = *reinterpret_cast<const unsigned*>(&XC[wid][r][2 * c]);
        else if (c < 24)
          val = *reinterpret_cast<const unsigned*>(
              &XM[wid][3 + r][16 + 2 * (c - 16)]);
        else
          val = (unsigned)(unsigned short)XM[wid][3 + r][32];
        rb[idx] = val;
      }
    }
  }
}

// ---- K2: fused segmented scan + carry.  1 block = (batch, 64-state group),
// all 8 segments.  128 blocks x 512 thr.
__global__ __launch_bounds__(512) void k_segcarry(float* __restrict__ Pb,
                                                  float* __restrict__ Hb,
                                                  float* __restrict__ carry) {
  __shared__ float sp[NSEG][64];
  __shared__ float sh_[NSEG][64];
  int t = threadIdx.x;
  int seg = t >> 6, stl = t & 63;
  int b = blockIdx.x >> 3, stg = blockIdx.x & 7;
  int st = stg * 64 + stl;
  size_t o = ((size_t)(b * NCH + seg * SEGC)) * 512 + st;
  float h = 0.f, p = 1.f;
#pragma unroll 4
  for (int c = 0; c < SEGC; c++) {
    float P = Pb[o], H = Hb[o];
    Pb[o] = p;
    Hb[o] = h;
    h = fmaf(P, h, H);
    p *= P;
    o += 512;
  }
  sp[seg][stl] = p;
  sh_[seg][stl] = h;
  __syncthreads();
  if (t < 64) {
    float hc = 0.f;
#pragma unroll
    for (int s = 0; s < NSEG; s++) {
      carry[(size_t)(b * NSEG + s) * 512 + st] = hc;
      hc = fmaf(sp[s][t], hc, sh_[s][t]);
    }
  }
}

// ---- K3: wave-private h0-correction + MFMA epilogue. 1 wave = 1 chunk.
// 256 thr = 4 chunks/block, grid 1024.  ONE barrier (Ads table).
__global__ __launch_bounds__(256) void k_mlp(
    const unsigned* __restrict__ rec, const float* __restrict__ x,
    const float* __restrict__ A_log, const float* __restrict__ Pb,
    const float* __restrict__ Hb, const float* __restrict__ carry,
    const float* __restrict__ dtw, const float* __restrict__ dtb,
    const float* __restrict__ rms1w, const float* __restrict__ ipw,
    const float* __restrict__ opw, const float* __restrict__ rms2w,
    const float* __restrict__ f1w, const float* __restrict__ f1b,
    const float* __restrict__ f2w, const float* __restrict__ f2b,
    const float* __restrict__ f3w, const float* __restrict__ f3b,
    float* __restrict__ out) {
  __shared__ float Ads[512];       // block-shared, pre-scaled by LOG2E
  __shared__ float h0w[4][512];    // wave-private h0
  __shared__ short sbx[4][32][24]; // x0 bf16
  __shared__ short sby[4][32][40]; // yfin -> yo -> x2 -> h1 -> h2 (bf16)
  int t = threadIdx.x;
  int l = t & 63, wid = t >> 6;
  int gc = blockIdx.x * 4 + wid;
  long row0 = (long)gc * CL;

  Ads[t] = -__expf(A_log[t]) * LOG2E;
  Ads[256 + t] = -__expf(A_log[256 + t]) * LOG2E;
  // h0 for this wave's chunk (8 states/lane)
  {
    size_t o = (size_t)gc * 512 + (size_t)(l * 8);
    int b = gc >> 8, seg = (gc >> 5) & 7;
    size_t co = (size_t)(b * NSEG + seg) * 512 + (size_t)(l * 8);
    float4 pv0 = *reinterpret_cast<const float4*>(Pb + o);
    float4 pv1 = *reinterpret_cast<const float4*>(Pb + o + 4);
    float4 hv0 = *reinterpret_cast<const float4*>(Hb + o);
    float4 hv1 = *reinterpret_cast<const float4*>(Hb + o + 4);
    float4 cv0 = *reinterpret_cast<const float4*>(carry + co);
    float4 cv1 = *reinterpret_cast<const float4*>(carry + co + 4);
    *reinterpret_cast<float4*>(&h0w[wid][l * 8]) =
        make_float4(fmaf(pv0.x, cv0.x, hv0.x), fmaf(pv0.y, cv0.y, hv0.y),
                    fmaf(pv0.z, cv0.z, hv0.z), fmaf(pv0.w, cv0.w, hv0.w));
    *reinterpret_cast<float4*>(&h0w[wid][l * 8 + 4]) =
        make_float4(fmaf(pv1.x, cv1.x, hv1.x), fmaf(pv1.y, cv1.y, hv1.y),
                    fmaf(pv1.z, cv1.z, hv1.z), fmaf(pv1.w, cv1.w, hv1.w));
  }
  // rmsnorm -> x0 bf16 (2 lanes/row)
  {
    int row = l >> 1, hf = l & 1;
    const float4* xp =
        reinterpret_cast<const float4*>(x + (row0 + row) * DMOD + hf * 8);
    float4 v0 = xp[0], v1 = xp[1];
    float xr[8] = {v0.x, v0.y, v0.z, v0.w, v1.x, v1.y, v1.z, v1.w};
    float ss = 0.f;
#pragma unroll
    for (int i = 0; i < 8; i++) ss += xr[i] * xr[i];
    ss += __shfl_xor(ss, 1);
    float inv1 = rsqrtf(ss * (1.f / 16.f) + 1e-6f);
    unsigned u[4];
#pragma unroll
    for (int i = 0; i < 4; i++)
      u[i] = packbf(xr[2 * i] * inv1 * rms1w[hf * 8 + 2 * i],
                    xr[2 * i + 1] * inv1 * rms1w[hf * 8 + 2 * i + 1]);
    *reinterpret_cast<uint4*>(&sbx[wid][row][hf * 8]) =
        make_uint4(u[0], u[1], u[2], u[3]);
  }
  __syncthreads();  // Ads table (block-shared)

  // correction: yfin = ypre + sum_s exp2(Ads*cumdt)*C*h0   (wave-private)
  {
    int half = l >> 5, r = l & 31;
    const unsigned* rb = rec + (size_t)gc * RECU;
    float Cv[16];
#pragma unroll
    for (int c = 0; c < 8; c++) {
      unsigned u = rb[(16 + c) * 32 + r];
      Cv[2 * c] = bflo(u);
      Cv[2 * c + 1] = bfhi(u);
    }
    float p0 = bflo(rb[24 * 32 + r]);
    const float* h0c = h0w[wid];
#pragma unroll
    for (int cc = 0; cc < 8; cc++) {
      int c = half * 8 + cc;
      int d0 = 2 * c, d1 = 2 * c + 1;
      float cd0 = fsoftplus(fmaf(p0, dtw[d0], dtb[d0]));
      float cd1 = fsoftplus(fmaf(p0, dtw[d1], dtb[d1]));
#pragma unroll
      for (int dl = 1; dl < 32; dl <<= 1) {
        float u0 = __shfl_up(cd0, dl, 32);
        float u1 = __shfl_up(cd1, dl, 32);
        if (r >= dl) { cd0 += u0; cd1 += u1; }
      }
      unsigned yu = rb[c * 32 + r];
      float acc0 = bflo(yu), acc1 = bfhi(yu);
      int dof0 = d0 * 16, dof1 = d1 * 16;
#pragma unroll
      for (int s = 0; s < 16; s++) {
        float e0 = __builtin_amdgcn_exp2f(Ads[dof0 + s] * cd0);
        float e1 = __builtin_amdgcn_exp2f(Ads[dof1 + s] * cd1);
        acc0 = fmaf(e0 * Cv[s], h0c[dof0 + s], acc0);
        acc1 = fmaf(e1 * Cv[s], h0c[dof1 + s], acc1);
      }
      *reinterpret_cast<unsigned*>(&sby[wid][r][2 * c]) = packbf(acc0, acc1);
    }
  }
  FENCE();

  // MFMA epilogue: this wave's 32 rows (2 tiles)
  {
    int col = l & 15, kg = l >> 4;
    bf16x8 Bz0 = bfrag(ipw + 32, 64, 0, col, kg, 16);
    bf16x8 Bz1 = bfrag(ipw + 32, 64, 16, col, kg, 16);
    bf16x8 Bop = bfrag(opw, 16, 0, col, kg, 32);
    bf16x8 Bf1_0 = bfrag(f1w, 32, 0, col, kg, 16);
    bf16x8 Bf1_1 = bfrag(f1w, 32, 16, col, kg, 16);
    bf16x8 Bf2_0 = bfrag(f2w, 32, 0, col, kg, 32);
    bf16x8 Bf2_1 = bfrag(f2w, 32, 16, col, kg, 32);
    bf16x8 Bf3 = bfrag(f3w, 16, 0, col, kg, 32);
    float b1_0 = f1b[col], b1_1 = f1b[16 + col];
    float b2_0 = f2b[col], b2_1 = f2b[16 + col];
    float b3c = f3b[col], rw2 = rms2w[col];
    const f32x4 zero4 = {0.f, 0.f, 0.f, 0.f};
#pragma unroll 1
    for (int rt = 0; rt < 2; rt++) {
      int tile0 = rt * 16;
      bf16x8 ax0 = {0, 0, 0, 0, 0, 0, 0, 0};
      if (kg < 2)
        ax0 = *reinterpret_cast<const bf16x8*>(&sbx[wid][tile0 + col][kg * 8]);
      f32x4 zf0 = mm(ax0, Bz0, zero4);
      f32x4 zf1 = mm(ax0, Bz1, zero4);
#pragma unroll
      for (int reg = 0; reg < 4; reg++) {
        int lrow = tile0 + kg * 4 + reg;
        float y0 = bf2f(sby[wid][lrow][col]);
        float y1 = bf2f(sby[wid][lrow][16 + col]);
        unsigned p = packbf(y0 * fsilu(zf0[reg]), y1 * fsilu(zf1[reg]));
        sby[wid][lrow][col] = (short)(p & 0xffffu);
        sby[wid][lrow][16 + col] = (short)(p >> 16);
      }
      FENCE();
      bf16x8 ayo =
          *reinterpret_cast<const bf16x8*>(&sby[wid][tile0 + col][kg * 8]);
      f32x4 x1f = mm(ayo, Bop, zero4);
      float xres[4];
#pragma unroll
      for (int reg = 0; reg < 4; reg++) {
        long grow = row0 + tile0 + kg * 4 + reg;
        xres[reg] = x1f[reg] + x[grow * 16 + col];
      }
#pragma unroll
      for (int reg = 0; reg < 4; reg++) {
        float ss = xres[reg] * xres[reg];
        ss += __shfl_xor(ss, 1);
        ss += __shfl_xor(ss, 2);
        ss += __shfl_xor(ss, 4);
        ss += __shfl_xor(ss, 8);
        float inv2 = rsqrtf(ss * (1.f / 16.f) + 1e-6f);
        sby[wid][tile0 + kg * 4 + reg][col] = f2bf(xres[reg] * inv2 * rw2);
      }
      FENCE();
      bf16x8 ax2 = {0, 0, 0, 0, 0, 0, 0, 0};
      if (kg < 2)
        ax2 = *reinterpret_cast<const bf16x8*>(&sby[wid][tile0 + col][kg * 8]);
      f32x4 h1f0 = mm(ax2, Bf1_0, zero4);
      f32x4 h1f1 = mm(ax2, Bf1_1, zero4);
#pragma unroll
      for (int reg = 0; reg < 4; reg++) {
        int lrow = tile0 + kg * 4 + reg;
        unsigned p = packbf(fmaxf(h1f0[reg] + b1_0, 0.f),
                            fmaxf(h1f1[reg] + b1_1, 0.f));
        sby[wid][lrow][col] = (short)(p & 0xffffu);
        sby[wid][lrow][16 + col] = (short)(p >> 16);
      }
      FENCE();
      bf16x8 ah1 =
          *reinterpret_cast<const bf16x8*>(&sby[wid][tile0 + col][kg * 8]);
      f32x4 h2f0 = mm(ah1, Bf2_0, zero4);
      f32x4 h2f1 = mm(ah1, Bf2_1, zero4);
#pragma unroll
      for (int reg = 0; reg < 4; reg++) {
        int lrow = tile0 + kg * 4 + reg;
        unsigned p = packbf(fmaxf(h2f0[reg] + b2_0, 0.f),
                            fmaxf(h2f1[reg] + b2_1, 0.f));
        sby[wid][lrow][col] = (short)(p & 0xffffu);
        sby[wid][lrow][16 + col] = (short)(p >> 16);
      }
      FENCE();
      bf16x8 ah2 =
          *reinterpret_cast<const bf16x8*>(&sby[wid][tile0 + col][kg * 8]);
      f32x4 x3f = mm(ah2, Bf3, zero4);
#pragma unroll
      for (int reg = 0; reg < 4; reg++) {
        long grow = row0 + tile0 + kg * 4 + reg;
        out[grow * 16 + col] = xres[reg] + x3f[reg] + b3c;
      }
      FENCE();
    }
  }
}

extern "C" void kernel_launch(void* const* d_in, const int* in_sizes, int n_in,
                              void* d_out, int out_size, void* d_ws,
                              size_t ws_size, hipStream_t stream) {
  const float* x = (const float*)d_in[0];
  const float* rms1w = (const float*)d_in[1];
  const float* ipw = (const float*)d_in[2];
  const float* cw = (const float*)d_in[3];
  const float* cb = (const float*)d_in[4];
  const float* xpw = (const float*)d_in[5];
  const float* dtw = (const float*)d_in[6];
  const float* dtb = (const float*)d_in[7];
  const float* A_log = (const float*)d_in[8];
  const float* Dskip = (const float*)d_in[9];
  const float* opw = (const float*)d_in[10];
  const float* rms2w = (const float*)d_in[11];
  const float* f1w = (const float*)d_in[12];
  const float* f1b = (const float*)d_in[13];
  const float* f2w = (const float*)d_in[14];
  const float* f2b = (const float*)d_in[15];
  const float* f3w = (const float*)d_in[16];
  const float* f3b = (const float*)d_in[17];
  float* out = (float*)d_out;

  unsigned* rec = (unsigned*)d_ws;                     // 13.1 MiB
  float* Pb = (float*)(rec + (size_t)NCHT * RECU);     // 8 MiB
  float* Hb = Pb + SUMN;                               // 8 MiB
  float* carry = Hb + SUMN;                            // 256 KiB

  hipLaunchKernelGGL(k_prep, dim3(NROWS / 128), dim3(256), 0, stream, x, rms1w,
                     ipw, cw, cb, xpw, dtw, dtb, A_log, Dskip, rec, Pb, Hb);
  hipLaunchKernelGGL(k_segcarry, dim3(NBAT * 8), dim3(512), 0, stream, Pb, Hb,
                     carry);
  hipLaunchKernelGGL(k_mlp, dim3(NROWS / 128), dim3(256), 0, stream, rec, x,
                     A_log, Pb, Hb, carry, dtw, dtb, rms1w, ipw, opw, rms2w,
                     f1w, f1b, f2w, f2b, f3w, f3b, out);
}